// Round 9
// baseline (2271.636 us; speedup 1.0000x reference)
//
#include <hip/hip_runtime.h>
#include <hip/hip_fp16.h>

// ---------------------------------------------------------------------------
// GCN 2-layer forward: out = relu(A_hat @ relu(A_hat @ (X W1) + b1) W2 + b2)
// A_hat = D^-1/2 (A + I) D^-1/2.
// Normalization folded: g = dinv[row] * (X@W); agg_n = dinv[n]*(g[n] + sum g[src]).
// Gather table G in FP16.
// R8 post-mortem: ANY per-edge per-node scatter (CSR fill) costs ~70us on this
// chip -- uncoalescable atomic/store micro-ops, not line locality. So: NO CSR.
// Edges are binned once at 64-dst-node granularity (bin = dst>>6); the
// aggregator takes one workgroup per bin and accumulates into LDS fp32
// accumulators (ds_add_f32, lane-owned columns), writing node rows coalesced.
// Degree/dinv also come from the bins (LDS counters, no global atomics).
// Requires N <= 65536 (src packs into 16 bits).
// ---------------------------------------------------------------------------

#define TILE 4096   // edges per bin_kernel block

// ---- bin edges by dst>>6 into per-bin record arrays: rec = (d&63)<<16 | s ----
__global__ __launch_bounds__(256) void bin_kernel(const int* __restrict__ src,
                                                  const int* __restrict__ dst, int E,
                                                  int cap, int nbins,
                                                  int* __restrict__ binCnt,
                                                  unsigned* __restrict__ recs) {
    extern __shared__ int lds[];           // cnt[nbins] | gbase[nbins]
    int* cnt = lds;
    int* gbase = lds + nbins;
    int tid = threadIdx.x;
    for (int i = tid; i < nbins; i += 256) cnt[i] = 0;
    __syncthreads();

    int t0 = blockIdx.x * TILE;
    int tEnd = min(t0 + TILE, E);

    // pass 1: count per bin (LDS atomics)
    for (int e = t0 + tid; e < tEnd; e += 256)
        atomicAdd(&cnt[dst[e] >> 6], 1);
    __syncthreads();

    // reserve global space per bin (few hundred global atomics per block)
    for (int i = tid; i < nbins; i += 256) {
        int c = cnt[i];
        gbase[i] = (c > 0) ? atomicAdd(&binCnt[i], c) : 0;
        cnt[i] = 0;                        // reuse as local cursor
    }
    __syncthreads();

    // pass 2: place records (runs within a bin are consecutive global slots)
    for (int e = t0 + tid; e < tEnd; e += 256) {
        int d = dst[e];
        int s = src[e];
        int b = d >> 6;
        int r = atomicAdd(&cnt[b], 1);
        recs[(size_t)b * cap + gbase[b] + r] = ((unsigned)(d & 63) << 16) | (unsigned)s;
    }
}

// ---- per-bin degree count -> dinv (all counters in LDS, coalesced writes) ----
__global__ __launch_bounds__(256) void dinv_bins(const unsigned* __restrict__ recs,
                                                 const int* __restrict__ binCnt, int cap,
                                                 float* __restrict__ dinv, int N) {
    __shared__ int c64[64];
    int b = blockIdx.x, tid = threadIdx.x;
    if (tid < 64) c64[tid] = 0;
    __syncthreads();
    int cnt = binCnt[b];
    const unsigned* bin = recs + (size_t)b * cap;
    for (int i = tid; i < cnt; i += 256)
        atomicAdd(&c64[bin[i] >> 16], 1);
    __syncthreads();
    if (tid < 64) {
        int n = (b << 6) + tid;
        if (n < N) dinv[n] = rsqrtf((float)(c64[tid] + 1));   // +1 = self loop
    }
}

// ---- fp32 GEMM: Y[r,:] = half( dinv[r] * (X[r,:] @ W) ), 4x4 register tile ----
template <int COLS>
__global__ __launch_bounds__(256) void gemm_kernel(const float* __restrict__ X,
                                                   const float* __restrict__ W,
                                                   const float* __restrict__ dinv,
                                                   __half* __restrict__ Y, int N) {
    constexpr int CT = COLS / 4;
    constexpr int RT = 256 / CT;
    constexpr int ROWS = RT * 4;
    constexpr int LDT = ROWS + 4;
    __shared__ float xT[128 * LDT];        // x transposed: [k][r]

    int tid = threadIdx.x;
    int row0 = blockIdx.x * ROWS;
    int kk = tid & 127;
    for (int rr = tid >> 7; rr < ROWS; rr += 2) {
        int r = row0 + rr;
        xT[kk * LDT + rr] = (r < N) ? X[(size_t)r * 128 + kk] : 0.0f;
    }
    __syncthreads();

    int ct = tid % CT, rt = tid / CT;
    int c0 = ct * 4, r0 = rt * 4;
    float acc[4][4] = {};
    #pragma unroll 4
    for (int k = 0; k < 128; k++) {
        float4 xv = *(const float4*)&xT[k * LDT + r0];
        float4 wv = *(const float4*)&W[(size_t)k * COLS + c0];
        float xs[4] = {xv.x, xv.y, xv.z, xv.w};
        float ws[4] = {wv.x, wv.y, wv.z, wv.w};
        #pragma unroll
        for (int i = 0; i < 4; i++)
            #pragma unroll
            for (int j = 0; j < 4; j++)
                acc[i][j] = fmaf(xs[i], ws[j], acc[i][j]);
    }
    #pragma unroll
    for (int i = 0; i < 4; i++) {
        int r = row0 + r0 + i;
        if (r < N) {
            float sc = dinv[r];
            __half2 p0 = __floats2half2_rn(sc * acc[i][0], sc * acc[i][1]);
            __half2 p1 = __floats2half2_rn(sc * acc[i][2], sc * acc[i][3]);
            *(__half2*)&Y[(size_t)r * COLS + c0]     = p0;
            *(__half2*)&Y[(size_t)r * COLS + c0 + 2] = p1;
        }
    }
}

// ---- aggregation F=128: one WG per 64-node bin, LDS fp32 accumulators ----
// accx/accy planes [64][64]: lane l owns cols 2l,2l+1 -> 2-way bank alias (free)
__global__ __launch_bounds__(256) void agg_bins_128(const __half* __restrict__ G,
                                                    const unsigned* __restrict__ recs,
                                                    const int* __restrict__ binCnt, int cap,
                                                    const float* __restrict__ dinv,
                                                    const float* __restrict__ bias,
                                                    float* __restrict__ out, int N) {
    __shared__ float accx[64][64];
    __shared__ float accy[64][64];
    int b = blockIdx.x;
    int tid = threadIdx.x;
    int lane = tid & 63, wave = tid >> 6;

    for (int i = tid; i < 64 * 64; i += 256) {
        ((float*)accx)[i] = 0.0f;
        ((float*)accy)[i] = 0.0f;
    }
    __syncthreads();

    int cnt = binCnt[b];
    const unsigned* bin = recs + (size_t)b * cap;

    for (int base = wave * 64; base < cnt; base += 256) {
        int e = base + lane;
        unsigned rv = (e < cnt) ? bin[e] : 0u;
        int m = min(64, cnt - base);
        for (int j = 0; j < m; j++) {
            unsigned r = __shfl((int)rv, j);
            int s = (int)(r & 0xFFFFu);
            int d = (int)(r >> 16);
            float2 v = __half22float2(*(const __half2*)&G[(size_t)s * 128 + lane * 2]);
            atomicAdd(&accx[d][lane], v.x);
            atomicAdd(&accy[d][lane], v.y);
        }
    }
    __syncthreads();

    // epilogue: 4 waves x 16 rows, coalesced float2 stores
    float bx = bias[lane * 2], by = bias[lane * 2 + 1];
    for (int rr = 0; rr < 16; rr++) {
        int row = rr * 4 + wave;
        int n = (b << 6) + row;
        if (n < N) {
            float di = dinv[n];
            float2 self = __half22float2(*(const __half2*)&G[(size_t)n * 128 + lane * 2]);
            float ox = fmaxf(fmaf(di, accx[row][lane] + self.x, bx), 0.0f);
            float oy = fmaxf(fmaf(di, accy[row][lane] + self.y, by), 0.0f);
            *(float2*)&out[(size_t)n * 128 + lane * 2] = make_float2(ox, oy);
        }
    }
}

// ---- aggregation F=64: one WG per bin, single LDS plane, lane owns col l ----
__global__ __launch_bounds__(256) void agg_bins_64(const __half* __restrict__ G,
                                                   const unsigned* __restrict__ recs,
                                                   const int* __restrict__ binCnt, int cap,
                                                   const float* __restrict__ dinv,
                                                   const float* __restrict__ bias,
                                                   float* __restrict__ out, int N) {
    __shared__ float acc[64][64];
    int b = blockIdx.x;
    int tid = threadIdx.x;
    int lane = tid & 63, wave = tid >> 6;

    for (int i = tid; i < 64 * 64; i += 256) ((float*)acc)[i] = 0.0f;
    __syncthreads();

    int cnt = binCnt[b];
    const unsigned* bin = recs + (size_t)b * cap;

    for (int base = wave * 64; base < cnt; base += 256) {
        int e = base + lane;
        unsigned rv = (e < cnt) ? bin[e] : 0u;
        int m = min(64, cnt - base);
        for (int j = 0; j < m; j++) {
            unsigned r = __shfl((int)rv, j);
            int s = (int)(r & 0xFFFFu);
            int d = (int)(r >> 16);
            float v = __half2float(G[(size_t)s * 64 + lane]);
            atomicAdd(&acc[d][lane], v);
        }
    }
    __syncthreads();

    float bl = bias[lane];
    for (int rr = 0; rr < 16; rr++) {
        int row = rr * 4 + wave;
        int n = (b << 6) + row;
        if (n < N) {
            float di = dinv[n];
            float self = __half2float(G[(size_t)n * 64 + lane]);
            out[(size_t)n * 64 + lane] = fmaxf(fmaf(di, acc[row][lane] + self, bl), 0.0f);
        }
    }
}

extern "C" void kernel_launch(void* const* d_in, const int* in_sizes, int n_in,
                              void* d_out, int out_size, void* d_ws, size_t ws_size,
                              hipStream_t stream) {
    const float* x  = (const float*)d_in[0];
    const int*   ei = (const int*)d_in[1];
    const float* W1 = (const float*)d_in[2];
    const float* b1 = (const float*)d_in[3];
    const float* W2 = (const float*)d_in[4];
    const float* b2 = (const float*)d_in[5];
    float* out = (float*)d_out;

    const int HID  = in_sizes[3];          // 128
    const int F_IN = in_sizes[2] / HID;    // 128
    const int N    = in_sizes[0] / F_IN;   // 50000
    const int E    = in_sizes[1] / 2;      // 1.6M
    (void)n_in; (void)out_size; (void)ws_size;

    const int* src = ei;
    const int* dst = ei + E;

    const int nbins = (N + 63) >> 6;                       // 782
    const int mean = E / nbins;                            // ~2046
    const int cap = mean + 512;                            // >10 sigma slack

    // ---- carve workspace ----
    char* p = (char*)d_ws;
    auto carve = [&](size_t bytes) { void* q = (void*)p; p += (bytes + 255) & ~(size_t)255; return q; };
    int*      binCnt = (int*)     carve((size_t)nbins * 4);
    float*    dinv   = (float*)   carve((size_t)N * 4);
    unsigned* recs   = (unsigned*)carve((size_t)nbins * cap * 4);
    __half*   bufG   = (__half*)  carve((size_t)N * 128 * 2);  // fp16 gather table
    float*    bufB   = (float*)   carve((size_t)N * 128 * 4);  // h1 (post agg+relu)

    hipMemsetAsync(binCnt, 0, (size_t)nbins * 4, stream);

    // ---- bin edges (only pre-pass; no CSR, no scans, no per-node scatter) ----
    int numTiles = (E + TILE - 1) / TILE;
    size_t binLds = (size_t)nbins * 2 * 4;
    bin_kernel<<<numTiles, 256, binLds, stream>>>(src, dst, E, cap, nbins, binCnt, recs);
    dinv_bins<<<nbins, 256, 0, stream>>>(recs, binCnt, cap, dinv, N);

    // ---- layer 1: bufG = half(dinv*(x@W1)) ; bufB = relu(dinv*agg + b1) ----
    gemm_kernel<128><<<(N + 31) / 32, 256, 0, stream>>>(x, W1, dinv, bufG, N);
    agg_bins_128<<<nbins, 256, 0, stream>>>(bufG, recs, binCnt, cap, dinv, b1, bufB, N);

    // ---- layer 2: bufG = half(dinv*(bufB@W2)) ; out = relu(dinv*agg + b2) ----
    gemm_kernel<64><<<(N + 63) / 64, 256, 0, stream>>>(bufB, W2, dinv, bufG, N);
    agg_bins_64<<<nbins, 256, 0, stream>>>(bufG, recs, binCnt, cap, dinv, b2, out, N);
}

// Round 10
// 306.516 us; speedup vs baseline: 7.4111x; 7.4111x over previous
//
#include <hip/hip_runtime.h>
#include <hip/hip_fp16.h>

// ---------------------------------------------------------------------------
// GCN 2-layer forward: out = relu(A_hat @ relu(A_hat @ (X W1) + b1) W2 + b2)
// A_hat = D^-1/2 (A + I) D^-1/2.
// Normalization folded: g = dinv[row]*(X@W); agg_n = dinv[n]*(g[n]+sum g[src]).
// Gather table G in FP16.
// Structure (R9 post-mortem: binning cheap, LDS *float atomics* catastrophic;
// R3-R8: any per-node global scatter costs ~70us):
//   1) bin_kernel: edges binned by dst>>6 (782 bins), rec=(d&63)<<16|s.
//   2) dinv_bins: per-bin degree count in LDS -> dinv. No global atomics.
//   3) agg kernels: one WG per bin; in-LDS COUNTING SORT by local dst
//      (int atomics on 64 counters only), then R5-style register-accumulate
//      gather per node (broadcast LDS edge reads, half2 gathers, fp32 regs).
// No CSR, no scans, no per-node scatter, no LDS float atomics.
// Requires N <= 65536 (src packs into 16 bits).
// ---------------------------------------------------------------------------

#define TILE 4096      // edges per bin_kernel block
#define BIN_CAP 2560   // per-bin record capacity (mean 2046, sd ~45 -> 11 sigma)

// ---- bin edges by dst>>6: rec = (d&63)<<16 | s ----
__global__ __launch_bounds__(256) void bin_kernel(const int* __restrict__ src,
                                                  const int* __restrict__ dst, int E,
                                                  int nbins,
                                                  int* __restrict__ binCnt,
                                                  unsigned* __restrict__ recs) {
    extern __shared__ int lds[];           // cnt[nbins] | gbase[nbins]
    int* cnt = lds;
    int* gbase = lds + nbins;
    int tid = threadIdx.x;
    for (int i = tid; i < nbins; i += 256) cnt[i] = 0;
    __syncthreads();

    int t0 = blockIdx.x * TILE;
    int tEnd = min(t0 + TILE, E);

    // pass 1: count per bin (LDS int atomics)
    for (int e = t0 + tid; e < tEnd; e += 256)
        atomicAdd(&cnt[dst[e] >> 6], 1);
    __syncthreads();

    // reserve global space per bin
    for (int i = tid; i < nbins; i += 256) {
        int c = cnt[i];
        gbase[i] = (c > 0) ? atomicAdd(&binCnt[i], c) : 0;
        cnt[i] = 0;                        // reuse as local cursor
    }
    __syncthreads();

    // pass 2: place records (runs within a bin are consecutive global slots)
    for (int e = t0 + tid; e < tEnd; e += 256) {
        int d = dst[e];
        int s = src[e];
        int b = d >> 6;
        int r = atomicAdd(&cnt[b], 1);
        int g = gbase[b] + r;
        if (g < BIN_CAP)
            recs[(size_t)b * BIN_CAP + g] = ((unsigned)(d & 63) << 16) | (unsigned)s;
    }
}

// ---- per-bin degree -> dinv (LDS counters, coalesced output) ----
__global__ __launch_bounds__(256) void dinv_bins(const unsigned* __restrict__ recs,
                                                 const int* __restrict__ binCnt,
                                                 float* __restrict__ dinv, int N) {
    __shared__ int c64[64];
    int b = blockIdx.x, tid = threadIdx.x;
    if (tid < 64) c64[tid] = 0;
    __syncthreads();
    int cnt = min(binCnt[b], BIN_CAP);
    const unsigned* bin = recs + (size_t)b * BIN_CAP;
    for (int i = tid; i < cnt; i += 256)
        atomicAdd(&c64[bin[i] >> 16], 1);
    __syncthreads();
    if (tid < 64) {
        int n = (b << 6) + tid;
        if (n < N) dinv[n] = rsqrtf((float)(c64[tid] + 1));   // +1 = self loop
    }
}

// ---- fp32 GEMM: Y[r,:] = half( dinv[r] * (X[r,:] @ W) ), 4x4 register tile ----
template <int COLS>
__global__ __launch_bounds__(256) void gemm_kernel(const float* __restrict__ X,
                                                   const float* __restrict__ W,
                                                   const float* __restrict__ dinv,
                                                   __half* __restrict__ Y, int N) {
    constexpr int CT = COLS / 4;
    constexpr int RT = 256 / CT;
    constexpr int ROWS = RT * 4;
    constexpr int LDT = ROWS + 4;
    __shared__ float xT[128 * LDT];        // x transposed: [k][r]

    int tid = threadIdx.x;
    int row0 = blockIdx.x * ROWS;
    int kk = tid & 127;
    for (int rr = tid >> 7; rr < ROWS; rr += 2) {
        int r = row0 + rr;
        xT[kk * LDT + rr] = (r < N) ? X[(size_t)r * 128 + kk] : 0.0f;
    }
    __syncthreads();

    int ct = tid % CT, rt = tid / CT;
    int c0 = ct * 4, r0 = rt * 4;
    float acc[4][4] = {};
    #pragma unroll 4
    for (int k = 0; k < 128; k++) {
        float4 xv = *(const float4*)&xT[k * LDT + r0];
        float4 wv = *(const float4*)&W[(size_t)k * COLS + c0];
        float xs[4] = {xv.x, xv.y, xv.z, xv.w};
        float ws[4] = {wv.x, wv.y, wv.z, wv.w};
        #pragma unroll
        for (int i = 0; i < 4; i++)
            #pragma unroll
            for (int j = 0; j < 4; j++)
                acc[i][j] = fmaf(xs[i], ws[j], acc[i][j]);
    }
    #pragma unroll
    for (int i = 0; i < 4; i++) {
        int r = row0 + r0 + i;
        if (r < N) {
            float sc = dinv[r];
            __half2 p0 = __floats2half2_rn(sc * acc[i][0], sc * acc[i][1]);
            __half2 p1 = __floats2half2_rn(sc * acc[i][2], sc * acc[i][3]);
            *(__half2*)&Y[(size_t)r * COLS + c0]     = p0;
            *(__half2*)&Y[(size_t)r * COLS + c0 + 2] = p1;
        }
    }
}

// ---- agg F=128: one WG per bin; LDS counting sort, then wave-per-node ----
__global__ __launch_bounds__(256) void agg_sort_128(const __half* __restrict__ G,
                                                    const unsigned* __restrict__ recs,
                                                    const int* __restrict__ binCnt,
                                                    const float* __restrict__ dinv,
                                                    const float* __restrict__ bias,
                                                    float* __restrict__ out, int N) {
    __shared__ unsigned short sorted[BIN_CAP];
    __shared__ int c64[64];
    __shared__ int start[65];
    __shared__ int cursor[64];
    int b = blockIdx.x, tid = threadIdx.x;
    int lane = tid & 63, wave = tid >> 6;

    if (tid < 64) c64[tid] = 0;
    __syncthreads();
    int cnt = min(binCnt[b], BIN_CAP);
    const unsigned* bin = recs + (size_t)b * BIN_CAP;

    // count
    for (int i = tid; i < cnt; i += 256)
        atomicAdd(&c64[bin[i] >> 16], 1);
    __syncthreads();

    // wave-0 exclusive prefix scan of c64 (shfl, wave-synchronous)
    if (wave == 0) {
        int c = c64[lane];
        int v = c;
        #pragma unroll
        for (int off = 1; off < 64; off <<= 1) {
            int t = __shfl_up(v, off);
            if (lane >= off) v += t;
        }
        start[lane] = v - c;
        cursor[lane] = v - c;
        if (lane == 63) start[64] = v;
    }
    __syncthreads();

    // place (LDS int atomics on 64 cursors)
    for (int i = tid; i < cnt; i += 256) {
        unsigned r = bin[i];
        int pos = atomicAdd(&cursor[r >> 16], 1);
        sorted[pos] = (unsigned short)(r & 0xFFFFu);
    }
    __syncthreads();

    // each wave: 16 nodes, register accumulate, fp16 half2 gathers
    float bx = bias[lane * 2], by = bias[lane * 2 + 1];
    for (int rr = 0; rr < 16; rr++) {
        int row = wave * 16 + rr;
        int n = (b << 6) + row;
        if (n >= N) continue;
        int st = start[row], en = start[row + 1];
        float2 self = __half22float2(*(const __half2*)&G[(size_t)n * 128 + lane * 2]);
        float ax = self.x, ay = self.y;
        int j = st;
        for (; j + 8 <= en; j += 8) {
            int s0 = sorted[j],     s1 = sorted[j + 1];
            int s2 = sorted[j + 2], s3 = sorted[j + 3];
            int s4 = sorted[j + 4], s5 = sorted[j + 5];
            int s6 = sorted[j + 6], s7 = sorted[j + 7];
            float2 v0 = __half22float2(*(const __half2*)&G[(size_t)s0 * 128 + lane * 2]);
            float2 v1 = __half22float2(*(const __half2*)&G[(size_t)s1 * 128 + lane * 2]);
            float2 v2 = __half22float2(*(const __half2*)&G[(size_t)s2 * 128 + lane * 2]);
            float2 v3 = __half22float2(*(const __half2*)&G[(size_t)s3 * 128 + lane * 2]);
            float2 v4 = __half22float2(*(const __half2*)&G[(size_t)s4 * 128 + lane * 2]);
            float2 v5 = __half22float2(*(const __half2*)&G[(size_t)s5 * 128 + lane * 2]);
            float2 v6 = __half22float2(*(const __half2*)&G[(size_t)s6 * 128 + lane * 2]);
            float2 v7 = __half22float2(*(const __half2*)&G[(size_t)s7 * 128 + lane * 2]);
            ax += ((v0.x + v1.x) + (v2.x + v3.x)) + ((v4.x + v5.x) + (v6.x + v7.x));
            ay += ((v0.y + v1.y) + (v2.y + v3.y)) + ((v4.y + v5.y) + (v6.y + v7.y));
        }
        for (; j < en; j++) {
            int s = sorted[j];
            float2 v = __half22float2(*(const __half2*)&G[(size_t)s * 128 + lane * 2]);
            ax += v.x; ay += v.y;
        }
        float di = dinv[n];
        float ox = fmaxf(fmaf(di, ax, bx), 0.0f);
        float oy = fmaxf(fmaf(di, ay, by), 0.0f);
        *(float2*)&out[(size_t)n * 128 + lane * 2] = make_float2(ox, oy);
    }
}

// ---- agg F=64: one WG per bin; sort, then HALF-wave per node (half2 lanes) ----
__global__ __launch_bounds__(256) void agg_sort_64(const __half* __restrict__ G,
                                                   const unsigned* __restrict__ recs,
                                                   const int* __restrict__ binCnt,
                                                   const float* __restrict__ dinv,
                                                   const float* __restrict__ bias,
                                                   float* __restrict__ out, int N) {
    __shared__ unsigned short sorted[BIN_CAP];
    __shared__ int c64[64];
    __shared__ int start[65];
    __shared__ int cursor[64];
    int b = blockIdx.x, tid = threadIdx.x;
    int lane = tid & 63, wave = tid >> 6;
    int hl = lane & 31, side = lane >> 5;

    if (tid < 64) c64[tid] = 0;
    __syncthreads();
    int cnt = min(binCnt[b], BIN_CAP);
    const unsigned* bin = recs + (size_t)b * BIN_CAP;

    for (int i = tid; i < cnt; i += 256)
        atomicAdd(&c64[bin[i] >> 16], 1);
    __syncthreads();

    if (wave == 0) {
        int c = c64[lane];
        int v = c;
        #pragma unroll
        for (int off = 1; off < 64; off <<= 1) {
            int t = __shfl_up(v, off);
            if (lane >= off) v += t;
        }
        start[lane] = v - c;
        cursor[lane] = v - c;
        if (lane == 63) start[64] = v;
    }
    __syncthreads();

    for (int i = tid; i < cnt; i += 256) {
        unsigned r = bin[i];
        int pos = atomicAdd(&cursor[r >> 16], 1);
        sorted[pos] = (unsigned short)(r & 0xFFFFu);
    }
    __syncthreads();

    // each wave: 8 node-PAIRS; half-wave (32 lanes, half2) per node
    float bx = bias[hl * 2], by = bias[hl * 2 + 1];
    for (int pp = 0; pp < 8; pp++) {
        int row = wave * 16 + pp * 2 + side;
        int n = (b << 6) + row;
        bool live = (n < N);
        int st = live ? start[row] : 0;
        int en = live ? start[row + 1] : 0;
        float ax = 0.0f, ay = 0.0f;
        if (live) {
            float2 self = __half22float2(*(const __half2*)&G[(size_t)n * 64 + hl * 2]);
            ax = self.x; ay = self.y;
        }
        int j = st;
        for (; j + 4 <= en; j += 4) {
            int s0 = sorted[j],     s1 = sorted[j + 1];
            int s2 = sorted[j + 2], s3 = sorted[j + 3];
            float2 v0 = __half22float2(*(const __half2*)&G[(size_t)s0 * 64 + hl * 2]);
            float2 v1 = __half22float2(*(const __half2*)&G[(size_t)s1 * 64 + hl * 2]);
            float2 v2 = __half22float2(*(const __half2*)&G[(size_t)s2 * 64 + hl * 2]);
            float2 v3 = __half22float2(*(const __half2*)&G[(size_t)s3 * 64 + hl * 2]);
            ax += (v0.x + v1.x) + (v2.x + v3.x);
            ay += (v0.y + v1.y) + (v2.y + v3.y);
        }
        for (; j < en; j++) {
            int s = sorted[j];
            float2 v = __half22float2(*(const __half2*)&G[(size_t)s * 64 + hl * 2]);
            ax += v.x; ay += v.y;
        }
        if (live) {
            float di = dinv[n];
            float ox = fmaxf(fmaf(di, ax, bx), 0.0f);
            float oy = fmaxf(fmaf(di, ay, by), 0.0f);
            *(float2*)&out[(size_t)n * 64 + hl * 2] = make_float2(ox, oy);
        }
    }
}

extern "C" void kernel_launch(void* const* d_in, const int* in_sizes, int n_in,
                              void* d_out, int out_size, void* d_ws, size_t ws_size,
                              hipStream_t stream) {
    const float* x  = (const float*)d_in[0];
    const int*   ei = (const int*)d_in[1];
    const float* W1 = (const float*)d_in[2];
    const float* b1 = (const float*)d_in[3];
    const float* W2 = (const float*)d_in[4];
    const float* b2 = (const float*)d_in[5];
    float* out = (float*)d_out;

    const int HID  = in_sizes[3];          // 128
    const int F_IN = in_sizes[2] / HID;    // 128
    const int N    = in_sizes[0] / F_IN;   // 50000
    const int E    = in_sizes[1] / 2;      // 1.6M
    (void)n_in; (void)out_size; (void)ws_size;

    const int* src = ei;
    const int* dst = ei + E;

    const int nbins = (N + 63) >> 6;       // 782

    // ---- carve workspace ----
    char* p = (char*)d_ws;
    auto carve = [&](size_t bytes) { void* q = (void*)p; p += (bytes + 255) & ~(size_t)255; return q; };
    int*      binCnt = (int*)     carve((size_t)nbins * 4);
    float*    dinv   = (float*)   carve((size_t)N * 4);
    unsigned* recs   = (unsigned*)carve((size_t)nbins * BIN_CAP * 4);
    __half*   bufG   = (__half*)  carve((size_t)N * 128 * 2);  // fp16 gather table
    float*    bufB   = (float*)   carve((size_t)N * 128 * 4);  // h1 (post agg+relu)

    hipMemsetAsync(binCnt, 0, (size_t)nbins * 4, stream);

    // ---- bin edges + dinv (no CSR, no scans, no per-node scatter) ----
    int numTiles = (E + TILE - 1) / TILE;
    size_t binLds = (size_t)nbins * 2 * 4;
    bin_kernel<<<numTiles, 256, binLds, stream>>>(src, dst, E, nbins, binCnt, recs);
    dinv_bins<<<nbins, 256, 0, stream>>>(recs, binCnt, dinv, N);

    // ---- layer 1: bufG = half(dinv*(x@W1)) ; bufB = relu(dinv*agg + b1) ----
    gemm_kernel<128><<<(N + 31) / 32, 256, 0, stream>>>(x, W1, dinv, bufG, N);
    agg_sort_128<<<nbins, 256, 0, stream>>>(bufG, recs, binCnt, dinv, b1, bufB, N);

    // ---- layer 2: bufG = half(dinv*(bufB@W2)) ; out = relu(dinv*agg + b2) ----
    gemm_kernel<64><<<(N + 63) / 64, 256, 0, stream>>>(bufB, W2, dinv, bufG, N);
    agg_sort_64<<<nbins, 256, 0, stream>>>(bufG, recs, binCnt, dinv, b2, out, N);
}

// Round 11
// 269.601 us; speedup vs baseline: 8.4259x; 1.1369x over previous
//
#include <hip/hip_runtime.h>
#include <hip/hip_fp16.h>

// ---------------------------------------------------------------------------
// GCN 2-layer forward: out = relu(A_hat @ relu(A_hat @ (X W1) + b1) W2 + b2)
// A_hat = D^-1/2 (A + I) D^-1/2.
// Normalization folded: g = dinv[row]*(X@W); agg_n = dinv[n]*(g[n]+sum g[src]).
// Gather table G in FP16.
// Structure (validated R10): bin by dst>>6 -> per-bin LDS counting sort ->
// register-accumulate gathers. R10 showed agg latency-bound at 27% occupancy
// (grid-shape cap: 782 blocks x 4 waves = 12 waves/CU); R11 uses 512-thread
// blocks (8 waves) to double resident waves -> ~24 waves/CU latency hiding.
// Requires N <= 65536 (src packs into 16 bits).
// ---------------------------------------------------------------------------

#define TILE 4096      // edges per bin_kernel block
#define BIN_CAP 2560   // per-bin record capacity (mean 2046, sd ~45 -> 11 sigma)

// ---- bin edges by dst>>6: rec = (d&63)<<16 | s ----
__global__ __launch_bounds__(256) void bin_kernel(const int* __restrict__ src,
                                                  const int* __restrict__ dst, int E,
                                                  int nbins,
                                                  int* __restrict__ binCnt,
                                                  unsigned* __restrict__ recs) {
    extern __shared__ int lds[];           // cnt[nbins] | gbase[nbins]
    int* cnt = lds;
    int* gbase = lds + nbins;
    int tid = threadIdx.x;
    for (int i = tid; i < nbins; i += 256) cnt[i] = 0;
    __syncthreads();

    int t0 = blockIdx.x * TILE;
    int tEnd = min(t0 + TILE, E);

    // pass 1: count per bin (LDS int atomics)
    for (int e = t0 + tid; e < tEnd; e += 256)
        atomicAdd(&cnt[dst[e] >> 6], 1);
    __syncthreads();

    // reserve global space per bin
    for (int i = tid; i < nbins; i += 256) {
        int c = cnt[i];
        gbase[i] = (c > 0) ? atomicAdd(&binCnt[i], c) : 0;
        cnt[i] = 0;                        // reuse as local cursor
    }
    __syncthreads();

    // pass 2: place records (runs within a bin are consecutive global slots)
    for (int e = t0 + tid; e < tEnd; e += 256) {
        int d = dst[e];
        int s = src[e];
        int b = d >> 6;
        int r = atomicAdd(&cnt[b], 1);
        int g = gbase[b] + r;
        if (g < BIN_CAP)
            recs[(size_t)b * BIN_CAP + g] = ((unsigned)(d & 63) << 16) | (unsigned)s;
    }
}

// ---- per-bin degree -> dinv (LDS counters, coalesced output) ----
__global__ __launch_bounds__(256) void dinv_bins(const unsigned* __restrict__ recs,
                                                 const int* __restrict__ binCnt,
                                                 float* __restrict__ dinv, int N) {
    __shared__ int c64[64];
    int b = blockIdx.x, tid = threadIdx.x;
    if (tid < 64) c64[tid] = 0;
    __syncthreads();
    int cnt = min(binCnt[b], BIN_CAP);
    const unsigned* bin = recs + (size_t)b * BIN_CAP;
    for (int i = tid; i < cnt; i += 256)
        atomicAdd(&c64[bin[i] >> 16], 1);
    __syncthreads();
    if (tid < 64) {
        int n = (b << 6) + tid;
        if (n < N) dinv[n] = rsqrtf((float)(c64[tid] + 1));   // +1 = self loop
    }
}

// ---- fp32 GEMM: Y[r,:] = half( dinv[r] * (X[r,:] @ W) ), 4x4 register tile ----
template <int COLS>
__global__ __launch_bounds__(256) void gemm_kernel(const float* __restrict__ X,
                                                   const float* __restrict__ W,
                                                   const float* __restrict__ dinv,
                                                   __half* __restrict__ Y, int N) {
    constexpr int CT = COLS / 4;
    constexpr int RT = 256 / CT;
    constexpr int ROWS = RT * 4;
    constexpr int LDT = ROWS + 4;
    __shared__ float xT[128 * LDT];        // x transposed: [k][r]

    int tid = threadIdx.x;
    int row0 = blockIdx.x * ROWS;
    int kk = tid & 127;
    for (int rr = tid >> 7; rr < ROWS; rr += 2) {
        int r = row0 + rr;
        xT[kk * LDT + rr] = (r < N) ? X[(size_t)r * 128 + kk] : 0.0f;
    }
    __syncthreads();

    int ct = tid % CT, rt = tid / CT;
    int c0 = ct * 4, r0 = rt * 4;
    float acc[4][4] = {};
    #pragma unroll 4
    for (int k = 0; k < 128; k++) {
        float4 xv = *(const float4*)&xT[k * LDT + r0];
        float4 wv = *(const float4*)&W[(size_t)k * COLS + c0];
        float xs[4] = {xv.x, xv.y, xv.z, xv.w};
        float ws[4] = {wv.x, wv.y, wv.z, wv.w};
        #pragma unroll
        for (int i = 0; i < 4; i++)
            #pragma unroll
            for (int j = 0; j < 4; j++)
                acc[i][j] = fmaf(xs[i], ws[j], acc[i][j]);
    }
    #pragma unroll
    for (int i = 0; i < 4; i++) {
        int r = row0 + r0 + i;
        if (r < N) {
            float sc = dinv[r];
            __half2 p0 = __floats2half2_rn(sc * acc[i][0], sc * acc[i][1]);
            __half2 p1 = __floats2half2_rn(sc * acc[i][2], sc * acc[i][3]);
            *(__half2*)&Y[(size_t)r * COLS + c0]     = p0;
            *(__half2*)&Y[(size_t)r * COLS + c0 + 2] = p1;
        }
    }
}

// ---- agg F=128: one WG (512 thr, 8 waves) per bin; sort then wave-per-node ----
__global__ __launch_bounds__(512) void agg_sort_128(const __half* __restrict__ G,
                                                    const unsigned* __restrict__ recs,
                                                    const int* __restrict__ binCnt,
                                                    const float* __restrict__ dinv,
                                                    const float* __restrict__ bias,
                                                    float* __restrict__ out, int N) {
    __shared__ unsigned short sorted[BIN_CAP];
    __shared__ int c64[64];
    __shared__ int start[65];
    __shared__ int cursor[64];
    int b = blockIdx.x, tid = threadIdx.x;
    int lane = tid & 63, wave = tid >> 6;

    if (tid < 64) c64[tid] = 0;
    __syncthreads();
    int cnt = min(binCnt[b], BIN_CAP);
    const unsigned* bin = recs + (size_t)b * BIN_CAP;

    // count
    for (int i = tid; i < cnt; i += 512)
        atomicAdd(&c64[bin[i] >> 16], 1);
    __syncthreads();

    // wave-0 exclusive prefix scan of c64 (shfl, wave-synchronous)
    if (wave == 0) {
        int c = c64[lane];
        int v = c;
        #pragma unroll
        for (int off = 1; off < 64; off <<= 1) {
            int t = __shfl_up(v, off);
            if (lane >= off) v += t;
        }
        start[lane] = v - c;
        cursor[lane] = v - c;
        if (lane == 63) start[64] = v;
    }
    __syncthreads();

    // place (LDS int atomics on 64 cursors)
    for (int i = tid; i < cnt; i += 512) {
        unsigned r = bin[i];
        int pos = atomicAdd(&cursor[r >> 16], 1);
        sorted[pos] = (unsigned short)(r & 0xFFFFu);
    }
    __syncthreads();

    // each of 8 waves: 8 nodes, register accumulate, fp16 half2 gathers
    float bx = bias[lane * 2], by = bias[lane * 2 + 1];
    for (int rr = 0; rr < 8; rr++) {
        int row = wave * 8 + rr;
        int n = (b << 6) + row;
        if (n >= N) continue;
        int st = start[row], en = start[row + 1];
        float2 self = __half22float2(*(const __half2*)&G[(size_t)n * 128 + lane * 2]);
        float ax = self.x, ay = self.y;
        int j = st;
        for (; j + 8 <= en; j += 8) {
            int s0 = sorted[j],     s1 = sorted[j + 1];
            int s2 = sorted[j + 2], s3 = sorted[j + 3];
            int s4 = sorted[j + 4], s5 = sorted[j + 5];
            int s6 = sorted[j + 6], s7 = sorted[j + 7];
            float2 v0 = __half22float2(*(const __half2*)&G[(size_t)s0 * 128 + lane * 2]);
            float2 v1 = __half22float2(*(const __half2*)&G[(size_t)s1 * 128 + lane * 2]);
            float2 v2 = __half22float2(*(const __half2*)&G[(size_t)s2 * 128 + lane * 2]);
            float2 v3 = __half22float2(*(const __half2*)&G[(size_t)s3 * 128 + lane * 2]);
            float2 v4 = __half22float2(*(const __half2*)&G[(size_t)s4 * 128 + lane * 2]);
            float2 v5 = __half22float2(*(const __half2*)&G[(size_t)s5 * 128 + lane * 2]);
            float2 v6 = __half22float2(*(const __half2*)&G[(size_t)s6 * 128 + lane * 2]);
            float2 v7 = __half22float2(*(const __half2*)&G[(size_t)s7 * 128 + lane * 2]);
            ax += ((v0.x + v1.x) + (v2.x + v3.x)) + ((v4.x + v5.x) + (v6.x + v7.x));
            ay += ((v0.y + v1.y) + (v2.y + v3.y)) + ((v4.y + v5.y) + (v6.y + v7.y));
        }
        for (; j < en; j++) {
            int s = sorted[j];
            float2 v = __half22float2(*(const __half2*)&G[(size_t)s * 128 + lane * 2]);
            ax += v.x; ay += v.y;
        }
        float di = dinv[n];
        float ox = fmaxf(fmaf(di, ax, bx), 0.0f);
        float oy = fmaxf(fmaf(di, ay, by), 0.0f);
        *(float2*)&out[(size_t)n * 128 + lane * 2] = make_float2(ox, oy);
    }
}

// ---- agg F=64: one WG (512 thr) per bin; sort, then HALF-wave per node ----
__global__ __launch_bounds__(512) void agg_sort_64(const __half* __restrict__ G,
                                                   const unsigned* __restrict__ recs,
                                                   const int* __restrict__ binCnt,
                                                   const float* __restrict__ dinv,
                                                   const float* __restrict__ bias,
                                                   float* __restrict__ out, int N) {
    __shared__ unsigned short sorted[BIN_CAP];
    __shared__ int c64[64];
    __shared__ int start[65];
    __shared__ int cursor[64];
    int b = blockIdx.x, tid = threadIdx.x;
    int lane = tid & 63, wave = tid >> 6;
    int hl = lane & 31, side = lane >> 5;

    if (tid < 64) c64[tid] = 0;
    __syncthreads();
    int cnt = min(binCnt[b], BIN_CAP);
    const unsigned* bin = recs + (size_t)b * BIN_CAP;

    for (int i = tid; i < cnt; i += 512)
        atomicAdd(&c64[bin[i] >> 16], 1);
    __syncthreads();

    if (wave == 0) {
        int c = c64[lane];
        int v = c;
        #pragma unroll
        for (int off = 1; off < 64; off <<= 1) {
            int t = __shfl_up(v, off);
            if (lane >= off) v += t;
        }
        start[lane] = v - c;
        cursor[lane] = v - c;
        if (lane == 63) start[64] = v;
    }
    __syncthreads();

    for (int i = tid; i < cnt; i += 512) {
        unsigned r = bin[i];
        int pos = atomicAdd(&cursor[r >> 16], 1);
        sorted[pos] = (unsigned short)(r & 0xFFFFu);
    }
    __syncthreads();

    // each of 8 waves: 4 node-PAIRS; half-wave (32 lanes, half2) per node
    float bx = bias[hl * 2], by = bias[hl * 2 + 1];
    for (int pp = 0; pp < 4; pp++) {
        int row = wave * 8 + pp * 2 + side;
        int n = (b << 6) + row;
        bool live = (n < N);
        int st = live ? start[row] : 0;
        int en = live ? start[row + 1] : 0;
        float ax = 0.0f, ay = 0.0f;
        if (live) {
            float2 self = __half22float2(*(const __half2*)&G[(size_t)n * 64 + hl * 2]);
            ax = self.x; ay = self.y;
        }
        int j = st;
        for (; j + 4 <= en; j += 4) {
            int s0 = sorted[j],     s1 = sorted[j + 1];
            int s2 = sorted[j + 2], s3 = sorted[j + 3];
            float2 v0 = __half22float2(*(const __half2*)&G[(size_t)s0 * 64 + hl * 2]);
            float2 v1 = __half22float2(*(const __half2*)&G[(size_t)s1 * 64 + hl * 2]);
            float2 v2 = __half22float2(*(const __half2*)&G[(size_t)s2 * 64 + hl * 2]);
            float2 v3 = __half22float2(*(const __half2*)&G[(size_t)s3 * 64 + hl * 2]);
            ax += (v0.x + v1.x) + (v2.x + v3.x);
            ay += (v0.y + v1.y) + (v2.y + v3.y);
        }
        for (; j < en; j++) {
            int s = sorted[j];
            float2 v = __half22float2(*(const __half2*)&G[(size_t)s * 64 + hl * 2]);
            ax += v.x; ay += v.y;
        }
        if (live) {
            float di = dinv[n];
            float ox = fmaxf(fmaf(di, ax, bx), 0.0f);
            float oy = fmaxf(fmaf(di, ay, by), 0.0f);
            *(float2*)&out[(size_t)n * 64 + hl * 2] = make_float2(ox, oy);
        }
    }
}

extern "C" void kernel_launch(void* const* d_in, const int* in_sizes, int n_in,
                              void* d_out, int out_size, void* d_ws, size_t ws_size,
                              hipStream_t stream) {
    const float* x  = (const float*)d_in[0];
    const int*   ei = (const int*)d_in[1];
    const float* W1 = (const float*)d_in[2];
    const float* b1 = (const float*)d_in[3];
    const float* W2 = (const float*)d_in[4];
    const float* b2 = (const float*)d_in[5];
    float* out = (float*)d_out;

    const int HID  = in_sizes[3];          // 128
    const int F_IN = in_sizes[2] / HID;    // 128
    const int N    = in_sizes[0] / F_IN;   // 50000
    const int E    = in_sizes[1] / 2;      // 1.6M
    (void)n_in; (void)out_size; (void)ws_size;

    const int* src = ei;
    const int* dst = ei + E;

    const int nbins = (N + 63) >> 6;       // 782

    // ---- carve workspace ----
    char* p = (char*)d_ws;
    auto carve = [&](size_t bytes) { void* q = (void*)p; p += (bytes + 255) & ~(size_t)255; return q; };
    int*      binCnt = (int*)     carve((size_t)nbins * 4);
    float*    dinv   = (float*)   carve((size_t)N * 4);
    unsigned* recs   = (unsigned*)carve((size_t)nbins * BIN_CAP * 4);
    __half*   bufG   = (__half*)  carve((size_t)N * 128 * 2);  // fp16 gather table
    float*    bufB   = (float*)   carve((size_t)N * 128 * 4);  // h1 (post agg+relu)

    hipMemsetAsync(binCnt, 0, (size_t)nbins * 4, stream);

    // ---- bin edges + dinv (no CSR, no scans, no per-node scatter) ----
    int numTiles = (E + TILE - 1) / TILE;
    size_t binLds = (size_t)nbins * 2 * 4;
    bin_kernel<<<numTiles, 256, binLds, stream>>>(src, dst, E, nbins, binCnt, recs);
    dinv_bins<<<nbins, 256, 0, stream>>>(recs, binCnt, dinv, N);

    // ---- layer 1: bufG = half(dinv*(x@W1)) ; bufB = relu(dinv*agg + b1) ----
    gemm_kernel<128><<<(N + 31) / 32, 256, 0, stream>>>(x, W1, dinv, bufG, N);
    agg_sort_128<<<nbins, 512, 0, stream>>>(bufG, recs, binCnt, dinv, b1, bufB, N);

    // ---- layer 2: bufG = half(dinv*(bufB@W2)) ; out = relu(dinv*agg + b2) ----
    gemm_kernel<64><<<(N + 63) / 64, 256, 0, stream>>>(bufB, W2, dinv, bufG, N);
    agg_sort_64<<<nbins, 512, 0, stream>>>(bufG, recs, binCnt, dinv, b2, out, N);
}